// Round 3
// baseline (121.206 us; speedup 1.0000x reference)
//
#include <hip/hip_runtime.h>

#define N 8192

typedef float f32x4 __attribute__((ext_vector_type(4)));

// Store with maximal cache bypass: system scope (sc0 sc1) + non-temporal (nt).
// Goal: out's 256 MiB write stream must NOT allocate in the 256 MiB Infinity
// Cache, so A (exactly IC-sized) stays resident across pass1 -> pass2 -> the
// next graph replay.
__device__ __forceinline__ void nt_store_f4(const f32x4 v, f32x4* p) {
    asm volatile("global_store_dwordx4 %0, %1, off sc0 sc1 nt"
                 :: "v"(p), "v"(v)
                 : "memory");
}

// Kernel 1: one wave (64 lanes) per row. Each lane loads 32 float4 (128 floats),
// sums in f32, 6-step shfl_xor wave reduction. Lane 0 writes d^-1/2.
// Normal (caching) loads on purpose: we WANT A allocated in L3 here.
__global__ __launch_bounds__(256) void rowsum_kernel(const float* __restrict__ A,
                                                     float* __restrict__ dinv) {
    const int wave = threadIdx.x >> 6;
    const int lane = threadIdx.x & 63;
    const int row  = blockIdx.x * 4 + wave;   // grid = N/4 blocks of 4 waves

    const f32x4* arow = reinterpret_cast<const f32x4*>(A + (size_t)row * N);

    float s = 0.0f;
#pragma unroll
    for (int k = 0; k < 32; ++k) {
        f32x4 v = arow[k * 64 + lane];        // lanes contiguous -> 1KiB/wave/instr
        s += (v.x + v.y) + (v.z + v.w);
    }

#pragma unroll
    for (int off = 32; off >= 1; off >>= 1)
        s += __shfl_xor(s, off, 64);

    if (lane == 0)
        dinv[row] = 1.0f / sqrtf(s);
}

// Kernel 2: one block per row. out[i][j] = dinv[i] * A[i][j] * dinv[j].
// A reads normal (should hit IC-resident copy); out stores bypass the whole
// cache hierarchy (sc0 sc1 nt).
__global__ __launch_bounds__(256) void scale_kernel(const float* __restrict__ A,
                                                    const float* __restrict__ dinv,
                                                    float* __restrict__ out) {
    const int row = blockIdx.x;
    const float ri = dinv[row];                       // uniform scalar load

    const f32x4* a4 = reinterpret_cast<const f32x4*>(A   + (size_t)row * N);
    const f32x4* d4 = reinterpret_cast<const f32x4*>(dinv);
    f32x4*       o4 = reinterpret_cast<f32x4*>(out + (size_t)row * N);

#pragma unroll
    for (int k = 0; k < 8; ++k) {
        const int idx = k * 256 + threadIdx.x;        // 2048 f4 per row
        f32x4 a = a4[idx];
        f32x4 c = d4[idx];                            // 32 KB, L1/L2-hot
        f32x4 o = a * ri * c;
        nt_store_f4(o, &o4[idx]);
    }
}

extern "C" void kernel_launch(void* const* d_in, const int* in_sizes, int n_in,
                              void* d_out, int out_size, void* d_ws, size_t ws_size,
                              hipStream_t stream) {
    const float* A    = (const float*)d_in[0];
    float*       out  = (float*)d_out;
    float*       dinv = (float*)d_ws;   // N floats = 32 KB scratch

    // Pass 1: row sums -> d^-1/2 (allocates A into the Infinity Cache)
    rowsum_kernel<<<N / 4, 256, 0, stream>>>(A, dinv);

    // Pass 2: scale; out stores bypass L2 + IC
    scale_kernel<<<N, 256, 0, stream>>>(A, dinv, out);
}